// Round 12
// baseline (147.707 us; speedup 1.0000x reference)
//
#include <hip/hip_runtime.h>
#include <cmath>

// SSIM fused kernel for B=16, C=3, H=W=512 fp32 images.
// R12 = R11 chassis + DELAYED V-conv (one-row software pipeline).
// R11 post-mortem: depth-2 prefetch neutral -> VMEM latency falsified.
// Remaining theory: per-iteration serial chain H-conv(row i) -> V-conv
// (output i-10 reads rSD[j] of row i) = ~90cy+LDS latency critical path
// per row that 6 waves/SIMD can't fully hide.
// Fix: at iter i, BEFORE storing row i into ring slot j=i%11, the ring
// holds exactly rows i-11..i-1 = the taps of output row i-11. Compute
// that output instead (slots (j+k)%11, static). V-chain now depends only
// on PREVIOUS iterations -> compiler can interleave H's LDS reads/fma
// chain with V's 36 register-only ops in one region. Source order:
// H-conv into temps -> V-conv from old ring -> ring store (no WAR issue:
// store is after V's reads). Ring still 22 f32x2; unroll still 4x11;
// guard i<43 (one extra reg-only iteration for the last output row).
// Sentinels: VGPR <= 48, WRITE_SIZE ~24KB, SQ_LDS_BANK_CONFLICT ~0.
// Decision: neutral => barrier phase-lockstep floor, declare.

#define IMG_H 512
#define IMG_W 512
#define STRIPE 32
#define NSTR (IMG_H / STRIPE)      // 16
#define NPLANES 48                 // 16*3
#define NBLOCKS (NPLANES * NSTR)   // 768
#define SSIM_C1 (0.01f * 0.01f)
#define SSIM_C2 (0.03f * 0.03f)

typedef float f32x2 __attribute__((ext_vector_type(2)));

struct W2x11 { float2 w[11]; };   // pre-broadcast {w,w} pairs

__launch_bounds__(512, 2)
__global__ void ssim_main(const float* __restrict__ img1,
                          const float* __restrict__ img2,
                          float* __restrict__ blockSums, W2x11 wvp) {
    // slot s holds (sum, diff) of col s-5; cols 0..4 / 517..521 are halo
    __shared__ float2 tb[2][528];
    __shared__ float red[8];

    const int x = threadIdx.x;            // 0..511, one output column
    const int bid = blockIdx.x;
    const int plane = bid >> 4;           // /NSTR
    const int stripe = bid & (NSTR - 1);
    const int y0 = stripe * STRIPE;
    const size_t base = (size_t)plane * (IMG_H * IMG_W);

    // zero halo pads (s=d=0 == a=b=0 == reference zero padding)
    if (x < 10) {
        const int col = (x < 5) ? x : (x + 512);
        tb[0][col] = make_float2(0.f, 0.f);
        tb[1][col] = make_float2(0.f, 0.f);
    }

    // ring of H-filtered (S,D) and (Qs,Qd) pairs, static-indexed
    f32x2 rSD[11], rQ[11];
    float acc = 0.f;

    // depth-2 prefetch registers (kept from R11: free, VGPR unchanged)
    float pa = 0.f, pb = 0.f, na = 0.f, nb = 0.f;
    {
        const int r0 = y0 - 5;            // staged row 0
        const int r1 = y0 - 4;            // staged row 1
        if (r0 >= 0) {
            pa = img1[base + (size_t)r0 * IMG_W + x];
            pb = img2[base + (size_t)r0 * IMG_W + x];
        }
        if (r1 >= 0) {
            na = img1[base + (size_t)r1 * IMG_W + x];
            nb = img2[base + (size_t)r1 * IMG_W + x];
        }
    }

    int buf = 0;
#pragma unroll 1
    for (int c = 0; c < 4; ++c) {
#pragma unroll
        for (int j = 0; j < 11; ++j) {
            const int i = c * 11 + j;      // 0..43; work for i<43
            if (i < 43) {                  // block-uniform guard
                if (i < 42) {
                    // stage (sum, diff) into LDS
                    tb[buf][x + 5] = make_float2(pa + pb, pa - pb);
                    // rotate prefetch; issue load of staged row i+2
                    pa = na; pb = nb;
                    na = 0.f; nb = 0.f;
                    const int rn = y0 - 3 + i;     // = y0-5 + (i+2)
                    if (i + 2 < 42 && rn >= 0 && rn < IMG_H) {
                        const size_t rb = base + (size_t)rn * IMG_W;
                        na = img1[rb + x];
                        nb = img2[rb + x];
                    }
                    __syncthreads();
                }
                // H-conv of row i into temps (not yet stored to ring)
                f32x2 hSD = {0.f, 0.f}, hQ = {0.f, 0.f};
                if (i < 42) {
#pragma unroll
                    for (int k = 0; k < 11; ++k) {
                        const float2 t = tb[buf][x + k];   // ds_read_b64
                        f32x2 sd; sd.x = t.x; sd.y = t.y;
                        const f32x2 q = sd * sd;           // s^2, d^2
                        f32x2 w2; w2.x = wvp.w[k].x; w2.y = wvp.w[k].y;
                        hSD = __builtin_elementwise_fma(w2, sd, hSD);
                        hQ  = __builtin_elementwise_fma(w2, q,  hQ);
                    }
                }
                // DELAYED V-conv: output row i-11, taps = ring rows
                // i-11..i-1 at slots (j+k)%11 — independent of hSD/hQ,
                // interleavable with the H-chain above.
                if (i >= 11) {
                    f32x2 vSD = {0.f, 0.f}, vQ = {0.f, 0.f};
#pragma unroll
                    for (int k = 0; k < 11; ++k) {
                        const int s = (j + k) % 11;      // static per (j,k)
                        f32x2 w2; w2.x = wvp.w[k].x; w2.y = wvp.w[k].y;
                        vSD = __builtin_elementwise_fma(w2, rSD[s], vSD);
                        vQ  = __builtin_elementwise_fma(w2, rQ[s],  vQ);
                    }
                    // S = mu1+mu2, D = mu1-mu2; Qs = G*s^2, Qd = G*d^2
                    const float ss = vSD.x * vSD.x;
                    const float dd = vSD.y * vSD.y;
                    const float e1 = (ss - dd) * 0.5f;      // 2*mu1*mu2
                    const float e2 = (ss + dd) * 0.5f;      // mu1^2+mu2^2
                    const float f1 = (vQ.x - vQ.y) * 0.5f;  // 2*G*(ab)
                    const float f2 = (vQ.x + vQ.y) * 0.5f;  // G*(a^2+b^2)
                    const float num = (e1 + SSIM_C1) * ((f1 - e1) + SSIM_C2);
                    const float den = (e2 + SSIM_C1) * ((f2 - e2) + SSIM_C2);
                    acc = fmaf(num, __builtin_amdgcn_rcpf(den), acc);
                }
                if (i < 42) {
                    // ring store AFTER the V reads (evicts row i-11)
                    rSD[j] = hSD; rQ[j] = hQ;
                    buf ^= 1;
                }
            }
        }
    }

    // block reduction: wave shuffle, then 8 wave-sums via LDS
#pragma unroll
    for (int off = 32; off >= 1; off >>= 1)
        acc += __shfl_down(acc, off, 64);
    const int wave = x >> 6, lane = x & 63;
    if (lane == 0) red[wave] = acc;
    __syncthreads();
    if (x == 0) {
        float s = 0.f;
#pragma unroll
        for (int k = 0; k < 8; ++k) s += red[k];
        blockSums[bid] = s;
    }
}

__global__ void ssim_reduce(const float* __restrict__ bs,
                            float* __restrict__ out) {
    __shared__ double red[4];
    const int t = threadIdx.x;  // 256 threads
    double a = 0.0;
    for (int idx = t; idx < NBLOCKS; idx += 256) a += (double)bs[idx];
#pragma unroll
    for (int off = 32; off >= 1; off >>= 1)
        a += __shfl_down(a, off, 64);
    const int wave = t >> 6, lane = t & 63;
    if (lane == 0) red[wave] = a;
    __syncthreads();
    if (t == 0) {
        const double s = red[0] + red[1] + red[2] + red[3];
        out[0] = (float)(s / (double)((double)NPLANES * IMG_H * IMG_W));
    }
}

extern "C" void kernel_launch(void* const* d_in, const int* in_sizes, int n_in,
                              void* d_out, int out_size, void* d_ws, size_t ws_size,
                              hipStream_t stream) {
    const float* img1 = (const float*)d_in[0];
    const float* img2 = (const float*)d_in[1];
    float* out = (float*)d_out;
    float* bs = (float*)d_ws;   // 768 floats of scratch

    // Gaussian weights, faithful to reference: center 5.5, sigma 1.5
    W2x11 wv;
    double g[11], s = 0.0;
    for (int i = 0; i < 11; ++i) {
        const double d = (double)i - 5.5;
        g[i] = exp(-(d * d) / (2.0 * 1.5 * 1.5));
        s += g[i];
    }
    for (int i = 0; i < 11; ++i) {
        const float w = (float)(g[i] / s);
        wv.w[i] = make_float2(w, w);
    }

    ssim_main<<<NBLOCKS, 512, 0, stream>>>(img1, img2, bs, wv);
    ssim_reduce<<<1, 256, 0, stream>>>(bs, out);
}